// Round 1
// baseline (373.808 us; speedup 1.0000x reference)
//
#include <hip/hip_runtime.h>

#define N_NODES 10000
#define BATCH   8
#define IN_SZ   64
#define UNITS   64
#define WIDTH   512   // IN_SZ * BATCH
#define TOTAL_IN (BATCH * N_NODES * IN_SZ)  // 5,120,000

// ---------------------------------------------------------------------------
// k_transpose: inputs[b, n*64+i] -> x0[n, i*8+b]; also zero the CSR counts.
// ---------------------------------------------------------------------------
__global__ __launch_bounds__(256) void k_transpose(const float* __restrict__ in,
                                                   float* __restrict__ x0,
                                                   int* __restrict__ counts) {
    int gid = blockIdx.x * 256 + threadIdx.x;
    if (gid < N_NODES) counts[gid] = 0;
    if (gid < TOTAL_IN) {
        int b   = gid / (N_NODES * IN_SZ);
        int rem = gid - b * (N_NODES * IN_SZ);
        int n   = rem / IN_SZ;
        int i   = rem - n * IN_SZ;
        x0[(size_t)n * WIDTH + i * BATCH + b] = in[gid];
    }
}

// ---------------------------------------------------------------------------
// k_hist: row histogram for CSR build.
// ---------------------------------------------------------------------------
__global__ __launch_bounds__(256) void k_hist(const int* __restrict__ rows,
                                              int* __restrict__ counts, int nnz) {
    int e = blockIdx.x * 256 + threadIdx.x;
    if (e < nnz) atomicAdd(&counts[rows[e]], 1);
}

// ---------------------------------------------------------------------------
// k_scan: single-block exclusive scan of counts -> row_ptr; zero counts so
// they can be reused as scatter cursors.
// ---------------------------------------------------------------------------
__global__ __launch_bounds__(1024) void k_scan(int* __restrict__ counts,
                                               int* __restrict__ row_ptr, int n) {
    __shared__ int tmp[1024];
    __shared__ int s_carry;
    int t = threadIdx.x;
    if (t == 0) s_carry = 0;
    __syncthreads();
    for (int base = 0; base < n; base += 1024) {
        int i = base + t;
        int v = (i < n) ? counts[i] : 0;
        if (i < n) counts[i] = 0;
        tmp[t] = v;
        __syncthreads();
        for (int off = 1; off < 1024; off <<= 1) {
            int add = (t >= off) ? tmp[t - off] : 0;
            __syncthreads();
            tmp[t] += add;
            __syncthreads();
        }
        int incl  = tmp[t];
        int carry = s_carry;
        if (i < n) row_ptr[i] = carry + incl - v;
        __syncthreads();
        if (t == 1023) s_carry = carry + tmp[1023];
        __syncthreads();
    }
    if (t == 0) row_ptr[n] = s_carry;
}

// ---------------------------------------------------------------------------
// k_scatter: scatter COO edges into CSR order (order within a row arbitrary).
// ---------------------------------------------------------------------------
__global__ __launch_bounds__(256) void k_scatter(const int* __restrict__ rows,
                                                 const int* __restrict__ cols,
                                                 const float* __restrict__ vals,
                                                 const int* __restrict__ row_ptr,
                                                 int* __restrict__ cursor,
                                                 int* __restrict__ cols_s,
                                                 float* __restrict__ vals_s, int nnz) {
    int e = blockIdx.x * 256 + threadIdx.x;
    if (e >= nnz) return;
    int r   = rows[e];
    int pos = row_ptr[r] + atomicAdd(&cursor[r], 1);
    cols_s[pos] = cols[e];
    vals_s[pos] = vals[e];
}

// ---------------------------------------------------------------------------
// k_spmm: one block per row, 256 threads each owning a float2 of the 512-wide
// row. xout[row] = scale * (L @ xin)[row] - (xsub ? xsub[row] : 0)
// ---------------------------------------------------------------------------
__global__ __launch_bounds__(256) void k_spmm(const int* __restrict__ row_ptr,
                                              const int* __restrict__ cols_s,
                                              const float* __restrict__ vals_s,
                                              const float* __restrict__ xin,
                                              float* __restrict__ xout,
                                              const float* __restrict__ xsub,
                                              float scale) {
    __shared__ int   s_col[256];
    __shared__ float s_val[256];
    int row = blockIdx.x;
    int t   = threadIdx.x;
    int start = row_ptr[row];
    int end   = row_ptr[row + 1];
    float ax = 0.f, ay = 0.f;
    for (int base = start; base < end; base += 256) {
        int e = base + t;
        if (e < end) { s_col[t] = cols_s[e]; s_val[t] = vals_s[e]; }
        __syncthreads();
        int cnt = min(256, end - base);
        for (int j = 0; j < cnt; ++j) {
            float v = s_val[j];
            const float2* src = (const float2*)(xin + (size_t)s_col[j] * WIDTH);
            float2 x = src[t];
            ax += v * x.x;
            ay += v * x.y;
        }
        __syncthreads();
    }
    float2 o;
    if (xsub) {
        float2 s = ((const float2*)(xsub + (size_t)row * WIDTH))[t];
        o.x = scale * ax - s.x;
        o.y = scale * ay - s.y;
    } else {
        o.x = scale * ax;
        o.y = scale * ay;
    }
    ((float2*)(xout + (size_t)row * WIDTH))[t] = o;
}

// ---------------------------------------------------------------------------
// k_combine: out[b,n,u] = bias[u] + sum_{i,m} T_m[n, i*8+b] * W[(i*3+m)*64+u]
// Block = 4 nodes x 64 units; each thread owns one u of one node and all 8 b.
// A-values are wave-uniform LDS broadcasts (float4 pairs).
// ---------------------------------------------------------------------------
__global__ __launch_bounds__(256) void k_combine(const float* __restrict__ x0,
                                                 const float* __restrict__ x1,
                                                 const float* __restrict__ x2,
                                                 const float* __restrict__ W,
                                                 const float* __restrict__ bias,
                                                 float* __restrict__ out) {
    __shared__ float sA[4][3][WIDTH];
    int t     = threadIdx.x;
    int node0 = blockIdx.x * 4;

    const float* srcs[3] = {x0, x1, x2};
    // stage 4 nodes x 3 mats x 512 floats = 1536 float4, 6 per thread
    for (int v = 0; v < 6; ++v) {
        int li   = v * 256 + t;          // float4 index 0..1535
        int node = li / 384;             // 384 float4 per node
        int rem  = li - node * 384;
        int m    = rem / 128;
        int f4   = rem - m * 128;
        float4 val = ((const float4*)(srcs[m] + (size_t)(node0 + node) * WIDTH))[f4];
        ((float4*)&sA[node][m][0])[f4] = val;
    }
    __syncthreads();

    int u  = t & 63;
    int nl = t >> 6;
    int n  = node0 + nl;

    float acc[8];
    float bs = bias[u];
#pragma unroll
    for (int b = 0; b < 8; ++b) acc[b] = bs;

    for (int i = 0; i < 64; ++i) {
        float w0 = W[(i * 3 + 0) * 64 + u];
        float w1 = W[(i * 3 + 1) * 64 + u];
        float w2 = W[(i * 3 + 2) * 64 + u];
        const float4* a0 = (const float4*)&sA[nl][0][i * 8];
        const float4* a1 = (const float4*)&sA[nl][1][i * 8];
        const float4* a2 = (const float4*)&sA[nl][2][i * 8];
        float4 a0l = a0[0], a0h = a0[1];
        float4 a1l = a1[0], a1h = a1[1];
        float4 a2l = a2[0], a2h = a2[1];
        acc[0] += a0l.x * w0 + a1l.x * w1 + a2l.x * w2;
        acc[1] += a0l.y * w0 + a1l.y * w1 + a2l.y * w2;
        acc[2] += a0l.z * w0 + a1l.z * w1 + a2l.z * w2;
        acc[3] += a0l.w * w0 + a1l.w * w1 + a2l.w * w2;
        acc[4] += a0h.x * w0 + a1h.x * w1 + a2h.x * w2;
        acc[5] += a0h.y * w0 + a1h.y * w1 + a2h.y * w2;
        acc[6] += a0h.z * w0 + a1h.z * w1 + a2h.z * w2;
        acc[7] += a0h.w * w0 + a1h.w * w1 + a2h.w * w2;
    }

#pragma unroll
    for (int b = 0; b < 8; ++b)
        out[((size_t)b * N_NODES + n) * UNITS + u] = acc[b];
}

// ---------------------------------------------------------------------------
extern "C" void kernel_launch(void* const* d_in, const int* in_sizes, int n_in,
                              void* d_out, int out_size, void* d_ws, size_t ws_size,
                              hipStream_t stream) {
    const float* inputs = (const float*)d_in[0];
    const int*   rows   = (const int*)d_in[1];
    const int*   cols   = (const int*)d_in[2];
    const float* vals   = (const float*)d_in[3];
    const float* W      = (const float*)d_in[4];
    const float* bias   = (const float*)d_in[5];
    float*       out    = (float*)d_out;
    int nnz = in_sizes[1];

    char* p = (char*)d_ws;
    auto alloc = [&](size_t bytes) {
        char* r = p;
        p += (bytes + 255) & ~(size_t)255;
        return r;
    };
    float* x0      = (float*)alloc(sizeof(float) * (size_t)N_NODES * WIDTH);
    float* x1      = (float*)alloc(sizeof(float) * (size_t)N_NODES * WIDTH);
    float* x2      = (float*)alloc(sizeof(float) * (size_t)N_NODES * WIDTH);
    int*   row_ptr = (int*)alloc(sizeof(int) * (N_NODES + 1));
    int*   cursor  = (int*)alloc(sizeof(int) * N_NODES);
    int*   cols_s  = (int*)alloc(sizeof(int) * (size_t)nnz);
    float* vals_s  = (float*)alloc(sizeof(float) * (size_t)nnz);

    k_transpose<<<(TOTAL_IN + 255) / 256, 256, 0, stream>>>(inputs, x0, cursor);
    k_hist<<<(nnz + 255) / 256, 256, 0, stream>>>(rows, cursor, nnz);
    k_scan<<<1, 1024, 0, stream>>>(cursor, row_ptr, N_NODES);
    k_scatter<<<(nnz + 255) / 256, 256, 0, stream>>>(rows, cols, vals, row_ptr, cursor,
                                                     cols_s, vals_s, nnz);
    k_spmm<<<N_NODES, 256, 0, stream>>>(row_ptr, cols_s, vals_s, x0, x1, nullptr, 1.0f);
    k_spmm<<<N_NODES, 256, 0, stream>>>(row_ptr, cols_s, vals_s, x1, x2, x0, 2.0f);
    k_combine<<<N_NODES / 4, 256, 0, stream>>>(x0, x1, x2, W, bias, out);
}

// Round 2
// 270.049 us; speedup vs baseline: 1.3842x; 1.3842x over previous
//
#include <hip/hip_runtime.h>

#define N_NODES 10000
#define BATCH   8
#define IN_SZ   64
#define UNITS   64
#define WIDTH   512            // IN_SZ * BATCH (elements per node row)
#define ROW_U   256            // uints per bf16 row (512 bf16)
#define TOTAL_IN (BATCH * N_NODES * IN_SZ)

typedef unsigned int uint;

// ---- bf16 helpers (RNE) ----------------------------------------------------
__device__ inline float bf_lo(uint u) { return __uint_as_float(u << 16); }
__device__ inline float bf_hi(uint u) { return __uint_as_float(u & 0xFFFF0000u); }
__device__ inline uint  f2bf_bits(float f) {
    uint u = __float_as_uint(f);
    uint r = ((u >> 16) & 1u) + 0x7FFFu;
    return (u + r) >> 16;
}
__device__ inline uint pack2(float a, float b) {
    return f2bf_bits(a) | (f2bf_bits(b) << 16);
}

// ---------------------------------------------------------------------------
// k_transpose: in[b, n*64+i] (fp32) -> x0bf[n, i*8+b] (bf16), 4 nodes/block,
// staged through LDS so global reads AND writes are fully coalesced.
// Also zeroes the CSR count array (4 counters per block).
// ---------------------------------------------------------------------------
__global__ __launch_bounds__(256) void k_transpose(const float* __restrict__ in,
                                                   uint* __restrict__ x0bf,
                                                   int* __restrict__ counts) {
    __shared__ unsigned short s[4 * WIDTH];   // 4 KB
    int t     = threadIdx.x;
    int node0 = blockIdx.x * 4;

    if (t < 4) counts[blockIdx.x * 4 + t] = 0;

    int nl = t >> 6;          // node within block (wave index)
    int i  = t & 63;          // feature index
#pragma unroll
    for (int b = 0; b < 8; ++b) {
        float val = in[(size_t)b * (N_NODES * IN_SZ) + (size_t)(node0 + nl) * IN_SZ + i];
        s[nl * WIDTH + i * 8 + b] = (unsigned short)f2bf_bits(val);
    }
    __syncthreads();

    const uint2* ss = (const uint2*)s;        // 512 uint2 total (8B each)
    uint2* dst = (uint2*)x0bf;                // 128 uint2 per node row
#pragma unroll
    for (int v = 0; v < 2; ++v) {
        int li = v * 256 + t;                 // 0..511
        dst[(size_t)node0 * 128 + li] = ss[li];
    }
}

// ---------------------------------------------------------------------------
// k_hist: row histogram for CSR build.
// ---------------------------------------------------------------------------
__global__ __launch_bounds__(256) void k_hist(const int* __restrict__ rows,
                                              int* __restrict__ counts, int nnz) {
    int e = blockIdx.x * 256 + threadIdx.x;
    if (e < nnz) atomicAdd(&counts[rows[e]], 1);
}

// ---------------------------------------------------------------------------
// k_scan: single block, 256 threads. Each thread serially sums CHUNK=40
// counts, wave-shfl scan + LDS cross-wave combine, serial write-out.
// Also zeroes counts so they can be reused as scatter cursors.
// ---------------------------------------------------------------------------
#define CHUNK 40
__global__ __launch_bounds__(256) void k_scan(int* __restrict__ counts,
                                              int* __restrict__ row_ptr, int n) {
    __shared__ int wsum[4];
    int t    = threadIdx.x;
    int base = t * CHUNK;
    int local[CHUNK];
    int tot = 0;
#pragma unroll
    for (int j = 0; j < CHUNK; ++j) {
        int idx = base + j;
        int v   = (idx < n) ? counts[idx] : 0;
        if (idx < n) counts[idx] = 0;
        local[j] = v;
        tot += v;
    }
    int lane = t & 63, w = t >> 6;
    int s = tot;
#pragma unroll
    for (int off = 1; off < 64; off <<= 1) {
        int nv = __shfl_up(s, off);
        if (lane >= off) s += nv;
    }
    if (lane == 63) wsum[w] = s;
    __syncthreads();
    int woff = 0;
    for (int k = 0; k < 4; ++k) if (k < w) woff += wsum[k];
    int run = woff + s - tot;                 // exclusive prefix for this thread
#pragma unroll
    for (int j = 0; j < CHUNK; ++j) {
        int idx = base + j;
        if (idx < n) row_ptr[idx] = run;
        run += local[j];
    }
    if (t == 255) row_ptr[n] = woff + s;
}

// ---------------------------------------------------------------------------
// k_scatter: scatter COO edges into CSR order (order within a row arbitrary).
// ---------------------------------------------------------------------------
__global__ __launch_bounds__(256) void k_scatter(const int* __restrict__ rows,
                                                 const int* __restrict__ cols,
                                                 const float* __restrict__ vals,
                                                 const int* __restrict__ row_ptr,
                                                 int* __restrict__ cursor,
                                                 int* __restrict__ cols_s,
                                                 float* __restrict__ vals_s, int nnz) {
    int e = blockIdx.x * 256 + threadIdx.x;
    if (e >= nnz) return;
    int r   = rows[e];
    int pos = row_ptr[r] + atomicAdd(&cursor[r], 1);
    cols_s[pos] = cols[e];
    vals_s[pos] = vals[e];
}

// ---------------------------------------------------------------------------
// k_spmm: one block per row; 256 threads each own one uint (2 bf16 columns).
// fp32 accumulation; xout = scale*(L@xin) - xsub, stored bf16.
// ---------------------------------------------------------------------------
__global__ __launch_bounds__(256) void k_spmm(const int* __restrict__ row_ptr,
                                              const int* __restrict__ cols_s,
                                              const float* __restrict__ vals_s,
                                              const uint* __restrict__ xin,
                                              uint* __restrict__ xout,
                                              const uint* __restrict__ xsub,
                                              float scale) {
    __shared__ int   s_col[256];
    __shared__ float s_val[256];
    int row = blockIdx.x;
    int t   = threadIdx.x;
    int start = row_ptr[row];
    int end   = row_ptr[row + 1];
    float ax = 0.f, ay = 0.f;
    for (int base = start; base < end; base += 256) {
        int e = base + t;
        if (e < end) { s_col[t] = cols_s[e]; s_val[t] = vals_s[e]; }
        __syncthreads();
        int cnt = min(256, end - base);
        for (int j = 0; j < cnt; ++j) {
            float v = s_val[j];
            uint  x = xin[(size_t)s_col[j] * ROW_U + t];
            ax += v * bf_lo(x);
            ay += v * bf_hi(x);
        }
        __syncthreads();
    }
    float ox = scale * ax, oy = scale * ay;
    if (xsub) {
        uint sx = xsub[(size_t)row * ROW_U + t];
        ox -= bf_lo(sx);
        oy -= bf_hi(sx);
    }
    xout[(size_t)row * ROW_U + t] = pack2(ox, oy);
}

// ---------------------------------------------------------------------------
// k_combine: out[b,n,u] = bias[u] + sum_{i,m} T_m[n, i*8+b] * W[(i*3+m)*64+u]
// Block = 4 nodes x 64 units. W staged in LDS (48 KB); A-tiles unpacked to
// fp32 in LDS at staging so the inner loop is pure float4 broadcasts + FMA.
// ---------------------------------------------------------------------------
__global__ __launch_bounds__(256, 2) void k_combine(const uint* __restrict__ x0,
                                                    const uint* __restrict__ x1,
                                                    const uint* __restrict__ x2,
                                                    const float* __restrict__ W,
                                                    const float* __restrict__ bias,
                                                    float* __restrict__ out) {
    __shared__ float sA[4][3][WIDTH];     // 24 KB
    __shared__ float sW[192 * 64];        // 48 KB
    int t     = threadIdx.x;
    int node0 = blockIdx.x * 4;

    // stage W: 12288 floats = 3072 float4
#pragma unroll
    for (int v = 0; v < 12; ++v) {
        int li = v * 256 + t;
        ((float4*)sW)[li] = ((const float4*)W)[li];
    }

    // stage A: 4 nodes x 3 mats x 256 uints = 1536 uint2, unpack to fp32
    const uint* srcs[3] = {x0, x1, x2};
#pragma unroll
    for (int v = 0; v < 6; ++v) {
        int li   = v * 256 + t;           // 0..1535
        int node = li / 384;
        int rem  = li - node * 384;
        int m    = rem >> 7;              // /128
        int p    = rem & 127;             // uint2 within row
        uint2 val = ((const uint2*)(srcs[m] + (size_t)(node0 + node) * ROW_U))[p];
        float4 f;
        f.x = bf_lo(val.x); f.y = bf_hi(val.x);
        f.z = bf_lo(val.y); f.w = bf_hi(val.y);
        ((float4*)&sA[node][m][0])[p] = f;
    }
    __syncthreads();

    int u  = t & 63;
    int nl = t >> 6;
    int n  = node0 + nl;

    float acc[8];
    float bs = bias[u];
#pragma unroll
    for (int b = 0; b < 8; ++b) acc[b] = bs;

    for (int i = 0; i < 64; ++i) {
        float w0 = sW[(i * 3 + 0) * 64 + u];
        float w1 = sW[(i * 3 + 1) * 64 + u];
        float w2 = sW[(i * 3 + 2) * 64 + u];
        const float4* a0 = (const float4*)&sA[nl][0][i * 8];
        const float4* a1 = (const float4*)&sA[nl][1][i * 8];
        const float4* a2 = (const float4*)&sA[nl][2][i * 8];
        float4 a0l = a0[0], a0h = a0[1];
        float4 a1l = a1[0], a1h = a1[1];
        float4 a2l = a2[0], a2h = a2[1];
        acc[0] += a0l.x * w0 + a1l.x * w1 + a2l.x * w2;
        acc[1] += a0l.y * w0 + a1l.y * w1 + a2l.y * w2;
        acc[2] += a0l.z * w0 + a1l.z * w1 + a2l.z * w2;
        acc[3] += a0l.w * w0 + a1l.w * w1 + a2l.w * w2;
        acc[4] += a0h.x * w0 + a1h.x * w1 + a2h.x * w2;
        acc[5] += a0h.y * w0 + a1h.y * w1 + a2h.y * w2;
        acc[6] += a0h.z * w0 + a1h.z * w1 + a2h.z * w2;
        acc[7] += a0h.w * w0 + a1h.w * w1 + a2h.w * w2;
    }

#pragma unroll
    for (int b = 0; b < 8; ++b)
        out[((size_t)b * N_NODES + n) * UNITS + u] = acc[b];
}

// ---------------------------------------------------------------------------
extern "C" void kernel_launch(void* const* d_in, const int* in_sizes, int n_in,
                              void* d_out, int out_size, void* d_ws, size_t ws_size,
                              hipStream_t stream) {
    const float* inputs = (const float*)d_in[0];
    const int*   rows   = (const int*)d_in[1];
    const int*   cols   = (const int*)d_in[2];
    const float* vals   = (const float*)d_in[3];
    const float* W      = (const float*)d_in[4];
    const float* bias   = (const float*)d_in[5];
    float*       out    = (float*)d_out;
    int nnz = in_sizes[1];

    char* p = (char*)d_ws;
    auto alloc = [&](size_t bytes) {
        char* r = p;
        p += (bytes + 255) & ~(size_t)255;
        return r;
    };
    uint*  x0      = (uint*)alloc(sizeof(uint) * (size_t)N_NODES * ROW_U);
    uint*  x1      = (uint*)alloc(sizeof(uint) * (size_t)N_NODES * ROW_U);
    uint*  x2      = (uint*)alloc(sizeof(uint) * (size_t)N_NODES * ROW_U);
    int*   row_ptr = (int*)alloc(sizeof(int) * (N_NODES + 1));
    int*   cursor  = (int*)alloc(sizeof(int) * N_NODES);
    int*   cols_s  = (int*)alloc(sizeof(int) * (size_t)nnz);
    float* vals_s  = (float*)alloc(sizeof(float) * (size_t)nnz);

    k_transpose<<<N_NODES / 4, 256, 0, stream>>>(inputs, x0, cursor);
    k_hist<<<(nnz + 255) / 256, 256, 0, stream>>>(rows, cursor, nnz);
    k_scan<<<1, 256, 0, stream>>>(cursor, row_ptr, N_NODES);
    k_scatter<<<(nnz + 255) / 256, 256, 0, stream>>>(rows, cols, vals, row_ptr, cursor,
                                                     cols_s, vals_s, nnz);
    k_spmm<<<N_NODES, 256, 0, stream>>>(row_ptr, cols_s, vals_s, x0, x1, nullptr, 1.0f);
    k_spmm<<<N_NODES, 256, 0, stream>>>(row_ptr, cols_s, vals_s, x1, x2, x0, 2.0f);
    k_combine<<<N_NODES / 4, 256, 0, stream>>>(x0, x1, x2, W, bias, out);
}